// Round 6
// baseline (879.214 us; speedup 1.0000x reference)
//
#include <hip/hip_runtime.h>

// ---------------------------------------------------------------------------
// SelfAttention: B=8, C=256, CQ=128, N=4096
//   q = Wq x + bq ; k = Wk x + bk ; v = Wv x + bv   (per-pixel 1x1 conv)
//   S[b,m,n] = q_m.k_n ; A = softmax over m (per column n)
//   O[b,c,m] = sum_n v[c,n] A[m,n] ; y = gamma*O + x
//
// Inputs may be f32 or bf16 (runtime-detected). ws = 32 MiB:
//   K0 qkv : project. q2T[b][m][c]=q*log2e, kT[b][n][c], v[b][c][n] (bf16)
//   K1 stats: r[b][n] = 1 / sum_m exp2(S2[m,n])
//   K2 scale: v *= r[n] in place
//   K3 out : fused S->exp2->PV, ALL IN REGISTERS (R13)
//
// R12 post-mortem: occupancy never moved (grid 1024 = 4 blocks/CU caps it);
// 5 rounds of scheduling variants all ~266us. Shared structure in all of
// them: S -> exp2 -> et LDS write -> barrier -> et LDS read -> PV, 4-wave
// lockstep. The et round-trip exists only to transpose fragments.
// R13: LAYOUT IDENTITY makes the transpose free. S's D-frag
//   s[r] = E'[m=l15][n=quad*4+r]
// is exactly the B-frag of v_mfma_f32_16x16x16_bf16 (B[k=quad*4+e][col=l15]).
// And v[c][n] rows are exactly its A-frag (A[row=l15][k=quad*4+e], b64
// contiguous loads). So: acc[c-local=quad*4+r][m=l15] += A(v) x B(exp2 s) —
// no LDS, no shuffle, NO BARRIER in the loop. Wave owns n-strip w*16 mod 64
// end-to-end; 4 waves' partial O (disjoint n) reduced once at the end via
// 17KB LDS + 4 barriers, stored coalesced. Block 32m x 128c (ch split),
// grid 2048, acc 64 VGPR, q B-frags pinned in 32 VGPR, bounds(256,2).
// Cost: PV K=16 (2x instr, same FLOPs); k/v L2 traffic 2GB->4GB
// (512MB/XCD -> L2-BW floor ~120us). Occupancy ~25% BY DESIGN: if fast at
// low occupancy, barrier-convoy theory confirmed.
// ---------------------------------------------------------------------------

typedef unsigned short u16;
typedef __attribute__((ext_vector_type(8))) short bf16x8;
typedef __attribute__((ext_vector_type(4))) short bf16x4;
typedef __attribute__((ext_vector_type(4))) float f32x4;

__device__ __forceinline__ float bf2f(u16 u) {
  union { unsigned int i; float f; } v; v.i = ((unsigned int)u) << 16; return v.f;
}
__device__ __forceinline__ u16 f2bf(float f) {
  union { float f; unsigned int i; } v; v.f = f;
  unsigned int r = v.i + 0x7fffu + ((v.i >> 16) & 1u);  // RNE
  return (u16)(r >> 16);
}

// D = A(16x16) x B(16x16) + C via v_mfma_f32_16x16x16_bf16 (2-reg A/B).
__device__ __forceinline__ f32x4 mfma16(bf16x4 a, bf16x4 b, f32x4 c) {
  asm("v_mfma_f32_16x16x16_bf16 %0, %1, %2, %0" : "+v"(c) : "v"(a), "v"(b));
  return c;
}

#define NB 8
#define NC 256
#define NCQ 128
#define NN 4096
#define LOG2E 1.4426950408889634f

// nonzero if any of the first ns even-index u16 samples has exponent >= 0x90:
// impossible for genuine bf16 inputs here, ~44%/sample for f32 mantissa halves.
__device__ __forceinline__ int scan_bad(const u16* p, int ns, int tid) {
  int bad = 0;
  for (int i = tid; i < ns; i += 256) {
    const int e = (p[2 * i] >> 7) & 0xff;
    bad |= (e >= 0x90) ? 1 : 0;
  }
  return bad;
}

__device__ __forceinline__ bf16x8 load8(const u16* pb, const float* pf,
                                        size_t off, bool f) {
  if (!f) return *(const bf16x8*)(pb + off);
  const float4 a = *(const float4*)(pf + off);
  const float4 b = *(const float4*)(pf + off + 4);
  bf16x8 r;
  r[0] = (short)f2bf(a.x); r[1] = (short)f2bf(a.y);
  r[2] = (short)f2bf(a.z); r[3] = (short)f2bf(a.w);
  r[4] = (short)f2bf(b.x); r[5] = (short)f2bf(b.y);
  r[6] = (short)f2bf(b.z); r[7] = (short)f2bf(b.w);
  return r;
}

// ---------------------------------------------------------------- K0: QKV --
__global__ __launch_bounds__(256, 2) void qkv_kernel(
    const void* xv, const void* Wqv, const void* bqv, const void* Wkv,
    const void* bkv, const void* Wvv, const void* bvv,
    u16* __restrict__ q2T, u16* __restrict__ kT, u16* __restrict__ vout) {
  __shared__ __align__(16) u16 xT[64][264];
  __shared__ int fl[8];
  const int tid = threadIdx.x;
  const int bid = blockIdx.x;
  const int b = bid & 7, n0 = (bid >> 3) << 6;

  if (tid < 8) fl[tid] = 0;
  __syncthreads();
  if (scan_bad((const u16*)xv, 256, tid)) fl[0] = 1;
  if (scan_bad((const u16*)Wqv, 64, tid)) fl[1] = 1;
  if (scan_bad((const u16*)Wkv, 64, tid)) fl[2] = 1;
  if (scan_bad((const u16*)Wvv, 64, tid)) fl[3] = 1;
  if (scan_bad((const u16*)bqv, 64, tid)) fl[4] = 1;
  if (scan_bad((const u16*)bkv, 64, tid)) fl[5] = 1;
  if (scan_bad((const u16*)bvv, 64, tid)) fl[6] = 1;
  __syncthreads();
  const bool fx = fl[0] != 0;

  {  // stage x[b][c][n0..n0+63] transposed into LDS (thread = c)
    const int c = tid;
    const size_t roff = (size_t)(b * NC + c) * NN + n0;
    if (fx) {
      const float* xp = (const float*)xv + roff;
#pragma unroll
      for (int j = 0; j < 16; ++j) {
        const float4 t = *(const float4*)(xp + j * 4);
        xT[j * 4 + 0][c] = f2bf(t.x); xT[j * 4 + 1][c] = f2bf(t.y);
        xT[j * 4 + 2][c] = f2bf(t.z); xT[j * 4 + 3][c] = f2bf(t.w);
      }
    } else {
      const u16* xp = (const u16*)xv + roff;
#pragma unroll
      for (int j = 0; j < 8; ++j) {
        bf16x8 t = *(const bf16x8*)(xp + j * 8);
#pragma unroll
        for (int e = 0; e < 8; ++e) xT[j * 8 + e][c] = (u16)t[e];
      }
    }
  }
  __syncthreads();

  const int w = tid >> 6, lane = tid & 63, l15 = lane & 15, quad = lane >> 4;
  const u16* Wb; const float* Wf; const u16* Bb; const float* Bf;
  bool fW, fB; int obase = 0; u16* dstT = nullptr; float sc = 1.f;
  if (w == 0) {
    Wb = (const u16*)Wqv; Wf = (const float*)Wqv;
    Bb = (const u16*)bqv; Bf = (const float*)bqv;
    fW = fl[1]; fB = fl[4]; dstT = q2T; sc = LOG2E;
  } else if (w == 1) {
    Wb = (const u16*)Wkv; Wf = (const float*)Wkv;
    Bb = (const u16*)bkv; Bf = (const float*)bkv;
    fW = fl[2]; fB = fl[5]; dstT = kT;
  } else if (w == 2) {
    Wb = (const u16*)Wvv; Wf = (const float*)Wvv;
    Bb = (const u16*)bvv; Bf = (const float*)bvv;
    fW = fl[3]; fB = fl[6];
  } else {
    Wb = (const u16*)Wvv + 32768; Wf = (const float*)Wvv + 32768;
    Bb = (const u16*)bvv + 128;   Bf = (const float*)bvv + 128;
    fW = fl[3]; fB = fl[6]; obase = 128;
  }

  bf16x8 xfr[4][8];  // x B-frags (from LDS)
#pragma unroll
  for (int nt = 0; nt < 4; ++nt) {
    const u16* xp = &xT[nt * 16 + l15][quad * 8];
#pragma unroll
    for (int ks = 0; ks < 8; ++ks) xfr[nt][ks] = *(const bf16x8*)(xp + ks * 32);
  }

  for (int ot = 0; ot < 8; ++ot) {
    bf16x8 wfr[8];  // A-frag: row o = ot*16+l15, k = c
    const size_t wrow = (size_t)(ot * 16 + l15) * 256 + quad * 8;
#pragma unroll
    for (int ks = 0; ks < 8; ++ks) wfr[ks] = load8(Wb, Wf, wrow + ks * 32, fW);
    float bias[4];
    {
      const int boff = ot * 16 + quad * 4;
#pragma unroll
      for (int r = 0; r < 4; ++r)
        bias[r] = fB ? Bf[boff + r] : bf2f(Bb[boff + r]);
    }
#pragma unroll
    for (int nt = 0; nt < 4; ++nt) {
      f32x4 acc = {0.f, 0.f, 0.f, 0.f};
#pragma unroll
      for (int ks = 0; ks < 8; ++ks)
        acc = __builtin_amdgcn_mfma_f32_16x16x32_bf16(wfr[ks], xfr[nt][ks], acc, 0, 0, 0);
      const int n = n0 + nt * 16 + l15;  // D: col=n-local, row=o-local
      if (w < 2) {
        ushort4 st;
        st.x = f2bf((acc[0] + bias[0]) * sc); st.y = f2bf((acc[1] + bias[1]) * sc);
        st.z = f2bf((acc[2] + bias[2]) * sc); st.w = f2bf((acc[3] + bias[3]) * sc);
        *(ushort4*)(dstT + ((size_t)(b * NN + n)) * NCQ + ot * 16 + quad * 4) = st;
      } else {
        const int c = obase + ot * 16 + quad * 4;
#pragma unroll
        for (int r = 0; r < 4; ++r)
          vout[((size_t)(b * NC + c + r)) * NN + n] = f2bf(acc[r] + bias[r]);
      }
    }
  }
}

// ------------------------------------ K1: r[n] = 1 / sum_m exp2(S2[m,n]) --
// grid 512 = 8 b x 64 n-blocks; 512 threads = 8 waves, wave w covers m in
// [w*512, (w+1)*512) (32 iters). kf pinned (64 VGPR).
__global__ __launch_bounds__(512, 4) void stats_kernel(
    const u16* __restrict__ q2T, const u16* __restrict__ kT,
    float* __restrict__ rbuf) {
  __shared__ float zbuf[8][64];
  const int bid = blockIdx.x;
  const int b = bid & 7, n0 = (bid >> 3) << 6;
  const int tid = threadIdx.x;
  const int w = tid >> 6, lane = tid & 63, l15 = lane & 15, quad = lane >> 4;

  bf16x8 kf[4][4];  // loop-invariant k B-frags: row n0+nt*16+l15, k = c
  {
    const u16* kp = kT + ((size_t)(b * NN + n0 + l15)) * NCQ + quad * 8;
#pragma unroll
    for (int nt = 0; nt < 4; ++nt)
#pragma unroll
      for (int ks = 0; ks < 4; ++ks) {
        kf[nt][ks] = *(const bf16x8*)(kp + (size_t)(nt * 16) * NCQ + ks * 32);
        asm volatile("" : "+v"(kf[nt][ks]));  // pin: no remat into the loop
      }
  }

  const u16* qbase = q2T + ((size_t)(b * NN + w * 512 + l15)) * NCQ + quad * 8;
  float Z[4] = {0.f, 0.f, 0.f, 0.f};
  for (int it = 0; it < 32; ++it) {
    const u16* qp = qbase + (size_t)(it * 16) * NCQ;
    bf16x8 af[4];
#pragma unroll
    for (int ks = 0; ks < 4; ++ks) af[ks] = *(const bf16x8*)(qp + ks * 32);
#pragma unroll
    for (int nt = 0; nt < 4; ++nt) {
      f32x4 acc = {0.f, 0.f, 0.f, 0.f};
#pragma unroll
      for (int ks = 0; ks < 4; ++ks)
        acc = __builtin_amdgcn_mfma_f32_16x16x32_bf16(af[ks], kf[nt][ks], acc, 0, 0, 0);
      Z[nt] += __builtin_amdgcn_exp2f(acc[0]) + __builtin_amdgcn_exp2f(acc[1]) +
               __builtin_amdgcn_exp2f(acc[2]) + __builtin_amdgcn_exp2f(acc[3]);
    }
  }
#pragma unroll
  for (int nt = 0; nt < 4; ++nt) {
    float z = Z[nt];
    z += __shfl_xor(z, 16, 64);
    z += __shfl_xor(z, 32, 64);
    Z[nt] = z;
  }
  if (lane < 16) {
#pragma unroll
    for (int nt = 0; nt < 4; ++nt) zbuf[w][nt * 16 + lane] = Z[nt];
  }
  __syncthreads();
  if (tid < 64) {
    float z = 0.f;
#pragma unroll
    for (int ww = 0; ww < 8; ++ww) z += zbuf[ww][tid];
    rbuf[b * NN + n0 + tid] = 1.0f / z;
  }
}

// -------------------------------------------- K2: v[c][n] *= r[n] in place --
__global__ __launch_bounds__(256, 4) void scale_kernel(
    u16* __restrict__ vr, const float* __restrict__ rbuf) {
  const int flat = (blockIdx.x * 256 + threadIdx.x) * 8;
  const int n = flat & (NN - 1);
  const int b = flat >> 20;
  const float4 r0 = *(const float4*)(rbuf + (b << 12) + n);
  const float4 r1 = *(const float4*)(rbuf + (b << 12) + n + 4);
  const ushort4 a0 = *(const ushort4*)(vr + flat);
  const ushort4 a1 = *(const ushort4*)(vr + flat + 4);
  ushort4 s0, s1;
  s0.x = f2bf(bf2f(a0.x) * r0.x); s0.y = f2bf(bf2f(a0.y) * r0.y);
  s0.z = f2bf(bf2f(a0.z) * r0.z); s0.w = f2bf(bf2f(a0.w) * r0.w);
  s1.x = f2bf(bf2f(a1.x) * r1.x); s1.y = f2bf(bf2f(a1.y) * r1.y);
  s1.z = f2bf(bf2f(a1.z) * r1.z); s1.w = f2bf(bf2f(a1.w) * r1.w);
  *(ushort4*)(vr + flat) = s0;
  *(ushort4*)(vr + flat + 4) = s1;
}

// ---------------- K3: fused S -> exp2 -> PV, all in registers (R13) --------
// grid 2048 = 8 b x 128 m-blocks(32m) x 2 c-halves; 4 waves.
// Wave w owns n-strip (n0 + w*16) for ALL of S and PV; no barrier in loop.
// S (16x16x32): s[r] = S2[m=l15][n = n0+w*16+quad*4+r]  (kf A, qf B from regs)
// PV (16x16x16): acc[mg][ct] += A(v[c][n] b64 frag) x B(exp2(s) bf16x4)
//   -> acc holds O[c = ct*16+quad*4+r][m = m0+mg*16+l15], n-partial.
// End: 4 waves' partials summed in LDS Obuf (4 barriers), coalesced store.
__global__ __launch_bounds__(256, 2) void out_kernel(
    const u16* __restrict__ q2T, const u16* __restrict__ kT,
    const u16* __restrict__ vr,
    const void* xv, const void* gv,
    const void* bqv, const void* bkv, const void* bvv,
    void* outv) {
  __shared__ float Obuf[32][132];  // [m-local][c-local + pad]
  __shared__ int fl[2];
  const int tid = threadIdx.x;
  if (tid < 2) fl[tid] = 0;
  __syncthreads();
  if (scan_bad((const u16*)xv, 256, tid)) fl[0] = 1;
  if (scan_bad((const u16*)bqv, 64, tid) | scan_bad((const u16*)bkv, 64, tid) |
      scan_bad((const u16*)bvv, 64, tid)) fl[1] = 1;
  // fl is read only after the epilogue barriers; loop touches ws (bf16) only.

  const int bid = blockIdx.x;
  const int b = bid & 7;           // all blocks of batch b land on XCD b
  const int r7 = bid >> 3;
  const int ch = r7 & 1;
  const int m0 = (r7 >> 1) << 5;   // 32-m block
  const int w = tid >> 6, lane = tid & 63, l15 = lane & 15, quad = lane >> 4;

  bf16x8 qf[2][4];  // loop-invariant q B-frags (32 VGPR), pinned
  {
    const u16* qp = q2T + ((size_t)(b * NN + m0 + l15)) * NCQ + quad * 8;
#pragma unroll
    for (int mg = 0; mg < 2; ++mg)
#pragma unroll
      for (int ks = 0; ks < 4; ++ks) {
        qf[mg][ks] = *(const bf16x8*)(qp + (size_t)(mg * 16) * NCQ + ks * 32);
        asm volatile("" : "+v"(qf[mg][ks]));  // pin: no remat into the loop
      }
  }

  f32x4 acc[2][8];  // [mg][ct]
#pragma unroll
  for (int mg = 0; mg < 2; ++mg)
#pragma unroll
    for (int ct = 0; ct < 8; ++ct) acc[mg][ct] = (f32x4){0.f, 0.f, 0.f, 0.f};

  const u16* kb = kT + ((size_t)(b * NN + w * 16 + l15)) * NCQ + quad * 8;
  const u16* vb = vr + ((size_t)(b * NC + ch * 128 + l15)) * NN + w * 16 + quad * 4;

#pragma unroll 2
  for (int n0 = 0; n0 < NN; n0 += 64) {
    // k A-frags for this n-strip (16 rows x 128c), b128 coalesced
    bf16x8 kf[4];
#pragma unroll
    for (int ks = 0; ks < 4; ++ks)
      kf[ks] = *(const bf16x8*)(kb + (size_t)n0 * NCQ + ks * 32);
    // v A-frags: lane = v[ct*16+l15][n0+w*16+quad*4 .. +4], b64
    bf16x4 vf[8];
#pragma unroll
    for (int ct = 0; ct < 8; ++ct)
      vf[ct] = *(const bf16x4*)(vb + (size_t)(ct * 16) * NN + n0);
    // S + exp2 -> PV B-frags, entirely in-lane
    bf16x4 pf[2];
#pragma unroll
    for (int mg = 0; mg < 2; ++mg) {
      f32x4 s = {0.f, 0.f, 0.f, 0.f};
#pragma unroll
      for (int ks = 0; ks < 4; ++ks)
        s = __builtin_amdgcn_mfma_f32_16x16x32_bf16(kf[ks], qf[mg][ks], s, 0, 0, 0);
      bf16x4 ev;
      ev[0] = (short)f2bf(__builtin_amdgcn_exp2f(s[0]));
      ev[1] = (short)f2bf(__builtin_amdgcn_exp2f(s[1]));
      ev[2] = (short)f2bf(__builtin_amdgcn_exp2f(s[2]));
      ev[3] = (short)f2bf(__builtin_amdgcn_exp2f(s[3]));
      pf[mg] = ev;
    }
    // PV: 16 independent accumulate MFMAs
#pragma unroll
    for (int mg = 0; mg < 2; ++mg)
#pragma unroll
      for (int ct = 0; ct < 8; ++ct)
        acc[mg][ct] = mfma16(vf[ct], pf[mg], acc[mg][ct]);
  }

  // ---- cross-wave n-partial reduction in LDS (once per block) ----
  auto dump = [&](int add) {
#pragma unroll
    for (int mg = 0; mg < 2; ++mg)
#pragma unroll
      for (int ct = 0; ct < 8; ++ct) {
        float* p = &Obuf[mg * 16 + l15][ct * 16 + quad * 4];
        f32x4 t = acc[mg][ct];
        if (add) {
          const f32x4 o = *(const f32x4*)p;
          t[0] += o[0]; t[1] += o[1]; t[2] += o[2]; t[3] += o[3];
        }
        *(f32x4*)p = t;
      }
  };
  if (w == 0) dump(0);
  __syncthreads();
  if (w == 1) dump(1);
  __syncthreads();
  if (w == 2) dump(1);
  __syncthreads();
  if (w == 3) dump(1);
  __syncthreads();

  const bool fx = fl[0] != 0, fg = fl[1] != 0;
  const float g = fg ? ((const float*)gv)[0] : bf2f(((const u16*)gv)[0]);
  // thread t: c-row = t>>1 (0..127), m-half mh = (t&1)*16 -> 16 m contiguous
  {
    const int c = tid >> 1;
    const int mh = (tid & 1) << 4;
    float o[16];
#pragma unroll
    for (int j = 0; j < 16; ++j) o[j] = Obuf[mh + j][c];
    const size_t base = ((size_t)(b * NC + ch * 128 + c)) * NN + m0 + mh;
    if (fx) {
      const float* xp = (const float*)xv + base;
      float* op = (float*)outv + base;
#pragma unroll
      for (int jj = 0; jj < 4; ++jj) {
        const float4 xl = *(const float4*)(xp + jj * 4);
        float4 st;
        st.x = g * o[jj * 4 + 0] + xl.x; st.y = g * o[jj * 4 + 1] + xl.y;
        st.z = g * o[jj * 4 + 2] + xl.z; st.w = g * o[jj * 4 + 3] + xl.w;
        *(float4*)(op + jj * 4) = st;
      }
    } else {
      const u16* xp = (const u16*)xv + base;
      u16* op = (u16*)outv + base;
#pragma unroll
      for (int jj = 0; jj < 4; ++jj) {
        const ushort4 xl = *(const ushort4*)(xp + jj * 4);
        ushort4 st;
        st.x = f2bf(g * o[jj * 4 + 0] + bf2f(xl.x));
        st.y = f2bf(g * o[jj * 4 + 1] + bf2f(xl.y));
        st.z = f2bf(g * o[jj * 4 + 2] + bf2f(xl.z));
        st.w = f2bf(g * o[jj * 4 + 3] + bf2f(xl.w));
        *(ushort4*)(op + jj * 4) = st;
      }
    }
  }
}

// ---------------------------------------------------------------------------
extern "C" void kernel_launch(void* const* d_in, const int* in_sizes, int n_in,
                              void* d_out, int out_size, void* d_ws, size_t ws_size,
                              hipStream_t stream) {
  // ws: q2 8,388,608 | k 8,388,608 | v 16,777,216 = 32 MiB; r -> tail or d_out
  const size_t NEED = 33554432u;
  if (ws_size < NEED) return;

  char* ws = (char*)d_ws;
  u16* q2 = (u16*)(ws);
  u16* kk = (u16*)(ws + 8388608);
  u16* vv = (u16*)(ws + 16777216);
  float* rbuf = (ws_size >= NEED + 131072u) ? (float*)(ws + NEED) : (float*)d_out;

  qkv_kernel<<<512, 256, 0, stream>>>(d_in[0], d_in[1], d_in[2], d_in[3],
                                      d_in[4], d_in[5], d_in[6], q2, kk, vv);
  stats_kernel<<<512, 512, 0, stream>>>(q2, kk, rbuf);
  scale_kernel<<<4096, 256, 0, stream>>>(vv, rbuf);
  out_kernel<<<2048, 256, 0, stream>>>(q2, kk, vv, d_in[0], d_in[7],
                                       d_in[2], d_in[4], d_in[6], d_out);
}

// Round 7
// 431.068 us; speedup vs baseline: 2.0396x; 2.0396x over previous
//
#include <hip/hip_runtime.h>

// ---------------------------------------------------------------------------
// SelfAttention: B=8, C=256, CQ=128, N=4096
//   q = Wq x + bq ; k = Wk x + bk ; v = Wv x + bv   (per-pixel 1x1 conv)
//   S[b,m,n] = q_m.k_n ; A = softmax over m (per column n)
//   O[b,c,m] = sum_n v[c,n] A[m,n] ; y = gamma*O + x
//
// Inputs may be f32 or bf16 (runtime-detected). ws = 32 MiB:
//   K0 qkv : project. q2T[b][m][c]=q*log2e, kT[b][n][c], v[b][c][n] (bf16)
//   K1 stats: r[b][n] = 1 / sum_m exp2(S2[m,n])
//   K2 scale: v *= r[n] in place
//   K3 out : S-recompute -> exp2 -> LDS flip -> PV -> y = g*O + x
//
// R13 post-mortem: barrier-free fused kernel = 725us (2.7x WORSE; MfmaUtil
// 11.7): K=16 PV doubled issue slots, ch-split re-duplicated S, 32B scatter
// loads. Model fitting ALL rounds: effective MFMA-equiv rate is STRUCTURE-
// INVARIANT at ~0.45-0.49 PF (R7 120GFe/265us, R9 103/210, R12 120/266,
// stats 34/90, R13 206/725). No scheduling/LDS/prefetch/barrier change ever
// moved it; only WORK deltas moved dur (R9 = ch-split removal, -55us, rate
// const). R14: bank the work lever.
//   out : full 256-c blocks (NO ch split): 137 -> 103 GF-equiv. 64m x 256c,
//         512 thr / 8 waves (S: wave = m-half x 16n-strip; PV: 32c strip),
//         grid 512 = 2 blocks/CU. dbuf et, 1 barrier/iter (proven R7 body).
//   out : exp2->bf16 packing via v_cvt_pk_bf16_f32 (2 vals/instr, HW RNE)
//         instead of ~4-op manual RNE per value.
// Predicted: out 266 -> 205-220, MfmaUtil -> 26-28%, total -> ~375.
// ---------------------------------------------------------------------------

typedef unsigned short u16;
typedef __attribute__((ext_vector_type(8))) short bf16x8;
typedef __attribute__((ext_vector_type(4))) short bf16x4;
typedef __attribute__((ext_vector_type(4))) float f32x4;

__device__ __forceinline__ float bf2f(u16 u) {
  union { unsigned int i; float f; } v; v.i = ((unsigned int)u) << 16; return v.f;
}
__device__ __forceinline__ u16 f2bf(float f) {
  union { float f; unsigned int i; } v; v.f = f;
  unsigned int r = v.i + 0x7fffu + ((v.i >> 16) & 1u);  // RNE
  return (u16)(r >> 16);
}

// exp2 of 4 f32 -> 4 bf16 packed via v_cvt_pk_bf16_f32 (HW RNE, 2 vals/instr)
__device__ __forceinline__ bf16x4 exp2_pk4(f32x4 s) {
  const float e0 = __builtin_amdgcn_exp2f(s[0]);
  const float e1 = __builtin_amdgcn_exp2f(s[1]);
  const float e2 = __builtin_amdgcn_exp2f(s[2]);
  const float e3 = __builtin_amdgcn_exp2f(s[3]);
  union { unsigned int u[2]; bf16x4 v; } r;
  asm("v_cvt_pk_bf16_f32 %0, %1, %2" : "=v"(r.u[0]) : "v"(e0), "v"(e1));
  asm("v_cvt_pk_bf16_f32 %0, %1, %2" : "=v"(r.u[1]) : "v"(e2), "v"(e3));
  return r.v;
}

#define NB 8
#define NC 256
#define NCQ 128
#define NN 4096
#define LOG2E 1.4426950408889634f

// nonzero if any of the first ns even-index u16 samples has exponent >= 0x90:
// impossible for genuine bf16 inputs here, ~44%/sample for f32 mantissa halves.
__device__ __forceinline__ int scan_bad(const u16* p, int ns, int tid) {
  int bad = 0;
  for (int i = tid; i < ns; i += 256) {
    const int e = (p[2 * i] >> 7) & 0xff;
    bad |= (e >= 0x90) ? 1 : 0;
  }
  return bad;
}

__device__ __forceinline__ bf16x8 load8(const u16* pb, const float* pf,
                                        size_t off, bool f) {
  if (!f) return *(const bf16x8*)(pb + off);
  const float4 a = *(const float4*)(pf + off);
  const float4 b = *(const float4*)(pf + off + 4);
  bf16x8 r;
  r[0] = (short)f2bf(a.x); r[1] = (short)f2bf(a.y);
  r[2] = (short)f2bf(a.z); r[3] = (short)f2bf(a.w);
  r[4] = (short)f2bf(b.x); r[5] = (short)f2bf(b.y);
  r[6] = (short)f2bf(b.z); r[7] = (short)f2bf(b.w);
  return r;
}

// ---------------------------------------------------------------- K0: QKV --
__global__ __launch_bounds__(256, 2) void qkv_kernel(
    const void* xv, const void* Wqv, const void* bqv, const void* Wkv,
    const void* bkv, const void* Wvv, const void* bvv,
    u16* __restrict__ q2T, u16* __restrict__ kT, u16* __restrict__ vout) {
  __shared__ __align__(16) u16 xT[64][264];
  __shared__ int fl[8];
  const int tid = threadIdx.x;
  const int bid = blockIdx.x;
  const int b = bid & 7, n0 = (bid >> 3) << 6;

  if (tid < 8) fl[tid] = 0;
  __syncthreads();
  if (scan_bad((const u16*)xv, 256, tid)) fl[0] = 1;
  if (scan_bad((const u16*)Wqv, 64, tid)) fl[1] = 1;
  if (scan_bad((const u16*)Wkv, 64, tid)) fl[2] = 1;
  if (scan_bad((const u16*)Wvv, 64, tid)) fl[3] = 1;
  if (scan_bad((const u16*)bqv, 64, tid)) fl[4] = 1;
  if (scan_bad((const u16*)bkv, 64, tid)) fl[5] = 1;
  if (scan_bad((const u16*)bvv, 64, tid)) fl[6] = 1;
  __syncthreads();
  const bool fx = fl[0] != 0;

  {  // stage x[b][c][n0..n0+63] transposed into LDS (thread = c)
    const int c = tid;
    const size_t roff = (size_t)(b * NC + c) * NN + n0;
    if (fx) {
      const float* xp = (const float*)xv + roff;
#pragma unroll
      for (int j = 0; j < 16; ++j) {
        const float4 t = *(const float4*)(xp + j * 4);
        xT[j * 4 + 0][c] = f2bf(t.x); xT[j * 4 + 1][c] = f2bf(t.y);
        xT[j * 4 + 2][c] = f2bf(t.z); xT[j * 4 + 3][c] = f2bf(t.w);
      }
    } else {
      const u16* xp = (const u16*)xv + roff;
#pragma unroll
      for (int j = 0; j < 8; ++j) {
        bf16x8 t = *(const bf16x8*)(xp + j * 8);
#pragma unroll
        for (int e = 0; e < 8; ++e) xT[j * 8 + e][c] = (u16)t[e];
      }
    }
  }
  __syncthreads();

  const int w = tid >> 6, lane = tid & 63, l15 = lane & 15, quad = lane >> 4;
  const u16* Wb; const float* Wf; const u16* Bb; const float* Bf;
  bool fW, fB; int obase = 0; u16* dstT = nullptr; float sc = 1.f;
  if (w == 0) {
    Wb = (const u16*)Wqv; Wf = (const float*)Wqv;
    Bb = (const u16*)bqv; Bf = (const float*)bqv;
    fW = fl[1]; fB = fl[4]; dstT = q2T; sc = LOG2E;
  } else if (w == 1) {
    Wb = (const u16*)Wkv; Wf = (const float*)Wkv;
    Bb = (const u16*)bkv; Bf = (const float*)bkv;
    fW = fl[2]; fB = fl[5]; dstT = kT;
  } else if (w == 2) {
    Wb = (const u16*)Wvv; Wf = (const float*)Wvv;
    Bb = (const u16*)bvv; Bf = (const float*)bvv;
    fW = fl[3]; fB = fl[6];
  } else {
    Wb = (const u16*)Wvv + 32768; Wf = (const float*)Wvv + 32768;
    Bb = (const u16*)bvv + 128;   Bf = (const float*)bvv + 128;
    fW = fl[3]; fB = fl[6]; obase = 128;
  }

  bf16x8 xfr[4][8];  // x B-frags (from LDS)
#pragma unroll
  for (int nt = 0; nt < 4; ++nt) {
    const u16* xp = &xT[nt * 16 + l15][quad * 8];
#pragma unroll
    for (int ks = 0; ks < 8; ++ks) xfr[nt][ks] = *(const bf16x8*)(xp + ks * 32);
  }

  for (int ot = 0; ot < 8; ++ot) {
    bf16x8 wfr[8];  // A-frag: row o = ot*16+l15, k = c
    const size_t wrow = (size_t)(ot * 16 + l15) * 256 + quad * 8;
#pragma unroll
    for (int ks = 0; ks < 8; ++ks) wfr[ks] = load8(Wb, Wf, wrow + ks * 32, fW);
    float bias[4];
    {
      const int boff = ot * 16 + quad * 4;
#pragma unroll
      for (int r = 0; r < 4; ++r)
        bias[r] = fB ? Bf[boff + r] : bf2f(Bb[boff + r]);
    }
#pragma unroll
    for (int nt = 0; nt < 4; ++nt) {
      f32x4 acc = {0.f, 0.f, 0.f, 0.f};
#pragma unroll
      for (int ks = 0; ks < 8; ++ks)
        acc = __builtin_amdgcn_mfma_f32_16x16x32_bf16(wfr[ks], xfr[nt][ks], acc, 0, 0, 0);
      const int n = n0 + nt * 16 + l15;  // D: col=n-local, row=o-local
      if (w < 2) {
        ushort4 st;
        st.x = f2bf((acc[0] + bias[0]) * sc); st.y = f2bf((acc[1] + bias[1]) * sc);
        st.z = f2bf((acc[2] + bias[2]) * sc); st.w = f2bf((acc[3] + bias[3]) * sc);
        *(ushort4*)(dstT + ((size_t)(b * NN + n)) * NCQ + ot * 16 + quad * 4) = st;
      } else {
        const int c = obase + ot * 16 + quad * 4;
#pragma unroll
        for (int r = 0; r < 4; ++r)
          vout[((size_t)(b * NC + c + r)) * NN + n] = f2bf(acc[r] + bias[r]);
      }
    }
  }
}

// ------------------------------------ K1: r[n] = 1 / sum_m exp2(S2[m,n]) --
// grid 512 = 8 b x 64 n-blocks; 512 threads = 8 waves, wave w covers m in
// [w*512, (w+1)*512) (32 iters). kf pinned (64 VGPR).
__global__ __launch_bounds__(512, 4) void stats_kernel(
    const u16* __restrict__ q2T, const u16* __restrict__ kT,
    float* __restrict__ rbuf) {
  __shared__ float zbuf[8][64];
  const int bid = blockIdx.x;
  const int b = bid & 7, n0 = (bid >> 3) << 6;
  const int tid = threadIdx.x;
  const int w = tid >> 6, lane = tid & 63, l15 = lane & 15, quad = lane >> 4;

  bf16x8 kf[4][4];  // loop-invariant k B-frags: row n0+nt*16+l15, k = c
  {
    const u16* kp = kT + ((size_t)(b * NN + n0 + l15)) * NCQ + quad * 8;
#pragma unroll
    for (int nt = 0; nt < 4; ++nt)
#pragma unroll
      for (int ks = 0; ks < 4; ++ks) {
        kf[nt][ks] = *(const bf16x8*)(kp + (size_t)(nt * 16) * NCQ + ks * 32);
        asm volatile("" : "+v"(kf[nt][ks]));  // pin: no remat into the loop
      }
  }

  const u16* qbase = q2T + ((size_t)(b * NN + w * 512 + l15)) * NCQ + quad * 8;
  float Z[4] = {0.f, 0.f, 0.f, 0.f};
  for (int it = 0; it < 32; ++it) {
    const u16* qp = qbase + (size_t)(it * 16) * NCQ;
    bf16x8 af[4];
#pragma unroll
    for (int ks = 0; ks < 4; ++ks) af[ks] = *(const bf16x8*)(qp + ks * 32);
#pragma unroll
    for (int nt = 0; nt < 4; ++nt) {
      f32x4 acc = {0.f, 0.f, 0.f, 0.f};
#pragma unroll
      for (int ks = 0; ks < 4; ++ks)
        acc = __builtin_amdgcn_mfma_f32_16x16x32_bf16(af[ks], kf[nt][ks], acc, 0, 0, 0);
      Z[nt] += __builtin_amdgcn_exp2f(acc[0]) + __builtin_amdgcn_exp2f(acc[1]) +
               __builtin_amdgcn_exp2f(acc[2]) + __builtin_amdgcn_exp2f(acc[3]);
    }
  }
#pragma unroll
  for (int nt = 0; nt < 4; ++nt) {
    float z = Z[nt];
    z += __shfl_xor(z, 16, 64);
    z += __shfl_xor(z, 32, 64);
    Z[nt] = z;
  }
  if (lane < 16) {
#pragma unroll
    for (int nt = 0; nt < 4; ++nt) zbuf[w][nt * 16 + lane] = Z[nt];
  }
  __syncthreads();
  if (tid < 64) {
    float z = 0.f;
#pragma unroll
    for (int ww = 0; ww < 8; ++ww) z += zbuf[ww][tid];
    rbuf[b * NN + n0 + tid] = 1.0f / z;
  }
}

// -------------------------------------------- K2: v[c][n] *= r[n] in place --
__global__ __launch_bounds__(256, 4) void scale_kernel(
    u16* __restrict__ vr, const float* __restrict__ rbuf) {
  const int flat = (blockIdx.x * 256 + threadIdx.x) * 8;
  const int n = flat & (NN - 1);
  const int b = flat >> 20;
  const float4 r0 = *(const float4*)(rbuf + (b << 12) + n);
  const float4 r1 = *(const float4*)(rbuf + (b << 12) + n + 4);
  const ushort4 a0 = *(const ushort4*)(vr + flat);
  const ushort4 a1 = *(const ushort4*)(vr + flat + 4);
  ushort4 s0, s1;
  s0.x = f2bf(bf2f(a0.x) * r0.x); s0.y = f2bf(bf2f(a0.y) * r0.y);
  s0.z = f2bf(bf2f(a0.z) * r0.z); s0.w = f2bf(bf2f(a0.w) * r0.w);
  s1.x = f2bf(bf2f(a1.x) * r1.x); s1.y = f2bf(bf2f(a1.y) * r1.y);
  s1.z = f2bf(bf2f(a1.z) * r1.z); s1.w = f2bf(bf2f(a1.w) * r1.w);
  *(ushort4*)(vr + flat) = s0;
  *(ushort4*)(vr + flat + 4) = s1;
}

// ------------ K3: E' = exp2(S2) recompute, O = E'.vr^T, y = g*O + x --------
// grid 512 = 8 b x 64 m-blocks (64m, FULL 256c -> S computed once).
// 512 threads = 8 waves. S-phase: wave w = (mh = w>>2) m-half x (nq = w&3)
// 16-n strip: 2 mg x 4 ks MFMA. PV-phase: wave w owns 32-c strip w*32:
// 4 mg x 2 ns x 2 ct MFMA. Per-wave-iter 24 MFMA / 8 global loads.
// dbuf et + 1 barrier/iter (R7's proven hazard scheme). 2 blocks/CU.
__global__ __launch_bounds__(512, 4) void out_kernel(
    const u16* __restrict__ q2T, const u16* __restrict__ kT,
    const u16* __restrict__ vr,
    const void* xv, const void* gv,
    const void* bqv, const void* bkv, const void* bvv,
    void* outv) {
  __shared__ __align__(16) u16 qs[64][136];
  __shared__ __align__(16) u16 et[2][4][16][68];
  __shared__ int fl[2];
  const int tid = threadIdx.x;
  if (tid < 2) fl[tid] = 0;
  __syncthreads();
  if (scan_bad((const u16*)xv, 256, tid)) fl[0] = 1;
  if (scan_bad((const u16*)bqv, 64, tid) | scan_bad((const u16*)bkv, 64, tid) |
      scan_bad((const u16*)bvv, 64, tid)) fl[1] = 1;

  const int bid = blockIdx.x;
  const int b = bid & 7;
  const int m0 = (bid >> 3) << 6;
  const int w = tid >> 6, lane = tid & 63, l15 = lane & 15, quad = lane >> 4;
  const int mh = w >> 2, nq = w & 3;

  {  // stage q2T[b][m0..m0+63][0..128) -> qs; thread t: row t>>3, 16 c
    const int mm = tid >> 3, ck = (tid & 7) * 16;
    const u16* src = q2T + ((size_t)(b * NN + m0 + mm)) * NCQ + ck;
#pragma unroll
    for (int j = 0; j < 2; ++j)
      *(bf16x8*)(&qs[mm][ck + j * 8]) = *(const bf16x8*)(src + j * 8);
  }
  __syncthreads();
  const bool fx = fl[0] != 0, fg = fl[1] != 0;

  f32x4 acc[8];  // acc[mg*2+ct]: m=m0+mg*16+quad*4+r, c=w*32+ct*16+l15
#pragma unroll
  for (int i = 0; i < 8; ++i) acc[i] = (f32x4){0.f, 0.f, 0.f, 0.f};

  const u16* kb = kT + ((size_t)(b * NN + nq * 16 + l15)) * NCQ + quad * 8;
  const u16* vb = vr + ((size_t)(b * NC + w * 32 + l15)) * NN + quad * 8;

  for (int n0 = 0; n0 < NN; n0 += 64) {
    const int pp = (n0 >> 6) & 1;
    // ---- 8 independent global loads, issued together ----
    bf16x8 kf[4], vf[4];
#pragma unroll
    for (int ks = 0; ks < 4; ++ks)
      kf[ks] = *(const bf16x8*)(kb + (size_t)n0 * NCQ + ks * 32);
#pragma unroll
    for (int ct = 0; ct < 2; ++ct)
#pragma unroll
      for (int ns = 0; ns < 2; ++ns)
        vf[ct * 2 + ns] =
            *(const bf16x8*)(vb + (size_t)(ct * 16) * NN + n0 + ns * 32);
    // ---- S phase: my m-half (2 mg) x my 16-n strip; q frags from LDS ----
#pragma unroll
    for (int mgl = 0; mgl < 2; ++mgl) {
      f32x4 s = {0.f, 0.f, 0.f, 0.f};
#pragma unroll
      for (int ks = 0; ks < 4; ++ks) {
        const bf16x8 qfr =
            *(const bf16x8*)(&qs[mh * 32 + mgl * 16 + l15][quad * 8 + ks * 32]);
        s = __builtin_amdgcn_mfma_f32_16x16x32_bf16(kf[ks], qfr, s, 0, 0, 0);
      }
      // s[r] = S2[m = m0+mh*32+mgl*16+l15][n = n0 + nq*16 + quad*4 + r]
      *(bf16x4*)(&et[pp][mh * 2 + mgl][l15][nq * 16 + quad * 4]) = exp2_pk4(s);
    }
    __syncthreads();
    // ---- PV phase: all 4 m-groups x my 32-c strip ----
#pragma unroll
    for (int mg = 0; mg < 4; ++mg)
#pragma unroll
      for (int ns = 0; ns < 2; ++ns) {
        const bf16x8 af = *(const bf16x8*)(&et[pp][mg][l15][ns * 32 + quad * 8]);
#pragma unroll
        for (int ct = 0; ct < 2; ++ct)
          acc[mg * 2 + ct] = __builtin_amdgcn_mfma_f32_16x16x32_bf16(
              af, vf[ct * 2 + ns], acc[mg * 2 + ct], 0, 0, 0);
      }
    // dbuf et: next iter's S writes the other buffer; the buffer PV just
    // read is overwritten only after the NEXT barrier (R7 scheme).
  }

  const float g = fg ? ((const float*)gv)[0] : bf2f(((const u16*)gv)[0]);
#pragma unroll
  for (int mg = 0; mg < 4; ++mg)
#pragma unroll
    for (int ct = 0; ct < 2; ++ct) {
      const int c = w * 32 + ct * 16 + l15;                      // D col = c
      const int m = m0 + mg * 16 + quad * 4;                     // D row = m
      const size_t base = ((size_t)(b * NC + c)) * NN + m;
      const f32x4 a = acc[mg * 2 + ct];
      if (fx) {
        const float4 xl = *(const float4*)((const float*)xv + base);
        float4 st;
        st.x = g * a[0] + xl.x; st.y = g * a[1] + xl.y;
        st.z = g * a[2] + xl.z; st.w = g * a[3] + xl.w;
        *(float4*)((float*)outv + base) = st;
      } else {
        const ushort4 xl = *(const ushort4*)((const u16*)xv + base);
        ushort4 st;
        st.x = f2bf(g * a[0] + bf2f(xl.x));
        st.y = f2bf(g * a[1] + bf2f(xl.y));
        st.z = f2bf(g * a[2] + bf2f(xl.z));
        st.w = f2bf(g * a[3] + bf2f(xl.w));
        *(ushort4*)((u16*)outv + base) = st;
      }
    }
}

// ---------------------------------------------------------------------------
extern "C" void kernel_launch(void* const* d_in, const int* in_sizes, int n_in,
                              void* d_out, int out_size, void* d_ws, size_t ws_size,
                              hipStream_t stream) {
  // ws: q2 8,388,608 | k 8,388,608 | v 16,777,216 = 32 MiB; r -> tail or d_out
  const size_t NEED = 33554432u;
  if (ws_size < NEED) return;

  char* ws = (char*)d_ws;
  u16* q2 = (u16*)(ws);
  u16* kk = (u16*)(ws + 8388608);
  u16* vv = (u16*)(ws + 16777216);
  float* rbuf = (ws_size >= NEED + 131072u) ? (float*)(ws + NEED) : (float*)d_out;

  qkv_kernel<<<512, 256, 0, stream>>>(d_in[0], d_in[1], d_in[2], d_in[3],
                                      d_in[4], d_in[5], d_in[6], q2, kk, vv);
  stats_kernel<<<512, 512, 0, stream>>>(q2, kk, rbuf);
  scale_kernel<<<4096, 256, 0, stream>>>(vv, rbuf);
  out_kernel<<<512, 512, 0, stream>>>(q2, kk, vv, d_in[0], d_in[7],
                                      d_in[2], d_in[4], d_in[6], d_out);
}